// Round 6
// baseline (639.390 us; speedup 1.0000x reference)
//
#include <hip/hip_runtime.h>
#include <hip/hip_bf16.h>

typedef unsigned short u16;
typedef __bf16 bf16x8 __attribute__((ext_vector_type(8)));
typedef float floatx4 __attribute__((ext_vector_type(4)));
typedef float floatx2 __attribute__((ext_vector_type(2)));

static constexpr int D = 128;

__device__ inline float bflo(unsigned u) { return __uint_as_float(u << 16); }
__device__ inline float bfhi(unsigned u) { return __uint_as_float(u & 0xffff0000u); }
__device__ inline unsigned packbf(float a, float b) {
    unsigned lo = __hip_bfloat16_raw(__float2bfloat16(a)).x;
    unsigned hi = __hip_bfloat16_raw(__float2bfloat16(b)).x;
    return lo | (hi << 16);
}

// ---------------- zero ints ----------------
__global__ void zero_int_kernel(int* __restrict__ p, int n) {
    int i = blockIdx.x * blockDim.x + threadIdx.x;
    int stride = gridDim.x * blockDim.x;
    for (; i < n; i += stride) p[i] = 0;
}

// ---------------- convert x fp32 -> bf16 (row-major) ----------------
__global__ void convert_kernel(const float4* __restrict__ x, ushort4* __restrict__ xb, int n4) {
    int i = blockIdx.x * blockDim.x + threadIdx.x;
    int stride = gridDim.x * blockDim.x;
    for (; i < n4; i += stride) {
        float4 v = x[i];
        ushort4 o;
        o.x = __hip_bfloat16_raw(__float2bfloat16(v.x)).x;
        o.y = __hip_bfloat16_raw(__float2bfloat16(v.y)).x;
        o.z = __hip_bfloat16_raw(__float2bfloat16(v.z)).x;
        o.w = __hip_bfloat16_raw(__float2bfloat16(v.w)).x;
        xb[i] = o;
    }
}

// ---------------- per-dst counts (all 3 types) ----------------
__global__ void count_kernel(const int* __restrict__ d0, const int* __restrict__ d1,
                             const int* __restrict__ d2, int* __restrict__ counts,
                             int N, int E) {
    int t = blockIdx.y;
    int e = blockIdx.x * blockDim.x + threadIdx.x;
    if (e < E) {
        const int* d = (t == 0) ? d0 : (t == 1) ? d1 : d2;
        atomicAdd(&counts[t * N + d[e]], 1);
    }
}

// ---------------- cursor init: wave scan + one atomic per wave ----------------
__global__ __launch_bounds__(256) void cursor_kernel(const int* __restrict__ counts,
                                                     int* __restrict__ cursor,
                                                     int* __restrict__ counters,
                                                     int N, int bpt) {
    int t = blockIdx.x / bpt;
    int n = (blockIdx.x - t * bpt) * 256 + threadIdx.x;
    int lane = threadIdx.x & 63;
    int v = (n < N) ? counts[t * N + n] : 0;
    int incl = v;
#pragma unroll
    for (int d = 1; d < 64; d <<= 1) {
        int s = __shfl_up(incl, d, 64);
        if (lane >= d) incl += s;
    }
    int total = __shfl(incl, 63, 64);
    int base = 0;
    if (lane == 63) base = atomicAdd(&counters[t], total);
    base = __shfl(base, 63, 64);
    if (n < N) cursor[t * N + n] = base + incl - v;
}

// ---------------- CSR scatter, slot-major ----------------
template <int A>
__global__ void scatter_kernel(const int* __restrict__ dst, const int* __restrict__ src,
                               int* __restrict__ cursor, int* __restrict__ csr, int E) {
    int e = blockIdx.x * blockDim.x + threadIdx.x;
    if (e < E) {
        int pos = atomicAdd(&cursor[dst[e]], 1);
#pragma unroll
        for (int s = 0; s < A; ++s) csr[(size_t)s * E + pos] = src[e * A + s];
    }
}

// ---------------- pack all weights -> bf16 MFMA B-fragment order ----------------
// Wp chunk c = (kt*8+t)*64+lane holds B[k=kt*32+(lane>>4)*8+j][n=t*16+(lane&15)], j=0..7
// k<128: WC^T; 128..255: WA0; 256..511: WA1; 512..895: WA2
__global__ void pack_kernel(const float* __restrict__ WC, const float* __restrict__ W0,
                            const float* __restrict__ W1, const float* __restrict__ W2,
                            u16* __restrict__ Wp) {
    int c = blockIdx.x * blockDim.x + threadIdx.x;
    if (c >= 28 * 8 * 64) return;
    int lane = c & 63, t = (c >> 6) & 7, kt = c >> 9;
    int nn = t * 16 + (lane & 15);
    int k0 = kt * 32 + (lane >> 4) * 8;
    u16 o[8];
#pragma unroll
    for (int j = 0; j < 8; ++j) {
        int k = k0 + j;
        float w = (k < 128) ? WC[nn * 128 + k]
                : (k < 256) ? W0[(k - 128) * 128 + nn]
                : (k < 512) ? W1[(k - 256) * 128 + nn]
                            : W2[(k - 512) * 128 + nn];
        o[j] = __hip_bfloat16_raw(__float2bfloat16(w)).x;
    }
    *(uint4*)(Wp + (size_t)c * 8) = *(uint4*)o;
}

// ---------------- aggregation: wave per (node,type,slot), bf16 gather ----------------
// AGF fragment layout: chunk ((qp*NBs + b)*64 + ((m&15)|(quad<<4))) of 8 bf16,
// qp = sg*4 + (li>>2), quad = li&3 (col block cb = sg*16 + li covers AG cols cb*8..cb*8+7)
__global__ __launch_bounds__(256) void agg_kernel(
    const u16* __restrict__ xb, const int* __restrict__ counts,
    const int* __restrict__ cursor, const int* __restrict__ csr,
    u16* __restrict__ AGF, int n0, int M, int N, int E, int NBs) {
    int gw = blockIdx.x * 4 + (threadIdx.x >> 6);
    if (gw >= 6 * M) return;
    int lane = threadIdx.x & 63, li = lane & 15, g = lane >> 4;
    // sg = gw / M, rem = gw % M  (chain of compares; 6*M < 2^31)
    int sg = 0, rem = gw;
    if (rem >= 3 * M) { sg = 3; rem -= 3 * M; }
    if (rem >= 2 * M) { sg += 2; rem -= 2 * M; }
    else if (rem >= M) { sg += 1; rem -= M; }
    int t = (sg == 0) ? 0 : (sg <= 2) ? 1 : 2;
    int n = n0 + rem;
    int deg = counts[t * N + n];
    int start = cursor[t * N + n] - deg;
    const int* cp = csr + (size_t)sg * E + start;

    floatx2 acc[4];
#pragma unroll
    for (int j = 0; j < 4; ++j) acc[j] = floatx2{0.f, 0.f};

    for (int c0 = 0; c0 < deg; c0 += 64) {
        int rl = (c0 + lane < deg) ? cp[c0 + lane] : 0;
        int lim = deg - c0;
        if (lim > 64) lim = 64;
        int iters = (lim + 3) >> 2;
#pragma unroll 2
        for (int k = 0; k < iters; ++k) {
            int idx = 4 * k + g;
            int r = __shfl(rl, idx & 63, 64);
            if (idx < lim) {
                uint4 v = *(const uint4*)(xb + (size_t)r * D + li * 8);
                acc[0] += floatx2{bflo(v.x), bfhi(v.x)};
                acc[1] += floatx2{bflo(v.y), bfhi(v.y)};
                acc[2] += floatx2{bflo(v.z), bfhi(v.z)};
                acc[3] += floatx2{bflo(v.w), bfhi(v.w)};
            }
        }
    }
#pragma unroll
    for (int j = 0; j < 4; ++j) {
        acc[j].x += __shfl_xor(acc[j].x, 16, 64);
        acc[j].y += __shfl_xor(acc[j].y, 16, 64);
        acc[j].x += __shfl_xor(acc[j].x, 32, 64);
        acc[j].y += __shfl_xor(acc[j].y, 32, 64);
    }
    if (g == 0) {
        float norm = (deg > 0) ? 1.0f / (float)deg : 0.0f;
        unsigned o0 = packbf(acc[0].x * norm, acc[0].y * norm);
        unsigned o1 = packbf(acc[1].x * norm, acc[1].y * norm);
        unsigned o2 = packbf(acc[2].x * norm, acc[2].y * norm);
        unsigned o3 = packbf(acc[3].x * norm, acc[3].y * norm);
        int qp = sg * 4 + (li >> 2);
        int quad = li & 3;
        size_t chunk = ((size_t)qp * NBs + (rem >> 4)) * 64 + ((rem & 15) | (quad << 4));
        *(uint4*)(AGF + chunk * 8) = make_uint4(o0, o1, o2, o3);
    }
}

// ---------------- final GEMM, no LDS, no barriers ----------------
// out[n] = x[n]@WC^T + bC + AG[n]@[WA*]; A-frags direct from global.
__global__ __launch_bounds__(256) void final_gemm_kernel(
    const float* __restrict__ x, const u16* __restrict__ AGF, const u16* __restrict__ Wp,
    const float* __restrict__ bC, float* __restrict__ out, int n0, int M, int NBs) {
    const int tid = threadIdx.x;
    const int wave = tid >> 6;
    const int lane = tid & 63;
    const int m0 = blockIdx.x * 128;

    floatx4 acc[2][8];
#pragma unroll
    for (int s = 0; s < 2; ++s)
#pragma unroll
        for (int t = 0; t < 8; ++t) acc[s][t] = floatx4{0.f, 0.f, 0.f, 0.f};

    // x-part: kt 0..3 (K=128), convert fp32 -> bf16 fragments in-register
#pragma unroll
    for (int kt = 0; kt < 4; ++kt) {
        bf16x8 af[2];
#pragma unroll
        for (int st = 0; st < 2; ++st) {
            int m = m0 + wave * 32 + st * 16 + (lane & 15);
            if (m > M - 1) m = M - 1;
            const float* p = x + (size_t)(n0 + m) * D + kt * 32 + (lane >> 4) * 8;
            float4 a = *(const float4*)p;
            float4 b = *(const float4*)(p + 4);
            uint4 u = make_uint4(packbf(a.x, a.y), packbf(a.z, a.w),
                                 packbf(b.x, b.y), packbf(b.z, b.w));
            af[st] = *(bf16x8*)&u;
        }
#pragma unroll
        for (int t = 0; t < 8; ++t) {
            bf16x8 bf = *(const bf16x8*)(Wp + ((size_t)(kt * 8 + t) * 64 + lane) * 8);
            acc[0][t] = __builtin_amdgcn_mfma_f32_16x16x32_bf16(af[0], bf, acc[0][t], 0, 0, 0);
            acc[1][t] = __builtin_amdgcn_mfma_f32_16x16x32_bf16(af[1], bf, acc[1][t], 0, 0, 0);
        }
    }
    // AG part: kt 4..27, fragments direct from AGF
#pragma unroll 4
    for (int kt = 4; kt < 28; ++kt) {
        int qp = kt - 4;
        bf16x8 af[2];
#pragma unroll
        for (int st = 0; st < 2; ++st) {
            int mb = m0 + wave * 32 + st * 16;
            if (mb > M - 1) mb = M - 1;
            af[st] = *(const bf16x8*)(AGF + (((size_t)qp * NBs + (mb >> 4)) * 64 + lane) * 8);
        }
#pragma unroll
        for (int t = 0; t < 8; ++t) {
            bf16x8 bf = *(const bf16x8*)(Wp + ((size_t)(kt * 8 + t) * 64 + lane) * 8);
            acc[0][t] = __builtin_amdgcn_mfma_f32_16x16x32_bf16(af[0], bf, acc[0][t], 0, 0, 0);
            acc[1][t] = __builtin_amdgcn_mfma_f32_16x16x32_bf16(af[1], bf, acc[1][t], 0, 0, 0);
        }
    }
    // epilogue
    float bc[8];
#pragma unroll
    for (int t = 0; t < 8; ++t) bc[t] = bC[16 * t + (lane & 15)];
#pragma unroll
    for (int st = 0; st < 2; ++st) {
#pragma unroll
        for (int r = 0; r < 4; ++r) {
            int e = m0 + wave * 32 + st * 16 + (lane >> 4) * 4 + r;
            if (e >= M) continue;
            size_t base = (size_t)(n0 + e) * D;
#pragma unroll
            for (int t = 0; t < 8; ++t)
                out[base + 16 * t + (lane & 15)] = acc[st][t][r] + bc[t];
        }
    }
}

extern "C" void kernel_launch(void* const* d_in, const int* in_sizes, int n_in,
                              void* d_out, int out_size, void* d_ws, size_t ws_size,
                              hipStream_t stream) {
    const float* x = (const float*)d_in[0];
    const int* src0 = (const int*)d_in[1];
    const int* dst0 = (const int*)d_in[2];
    const int* src1 = (const int*)d_in[3];
    const int* dst1 = (const int*)d_in[4];
    const int* src2 = (const int*)d_in[5];
    const int* dst2 = (const int*)d_in[6];
    const float* WA0 = (const float*)d_in[7];
    const float* WA1 = (const float*)d_in[8];
    const float* WA2 = (const float*)d_in[9];
    const float* WC = (const float*)d_in[10];
    const float* bC = (const float*)d_in[11];

    const int N = in_sizes[0] / D;  // 100000
    const int E = in_sizes[2];      // 500000

    auto align256 = [](size_t v) { return (v + 255) & ~(size_t)255; };
    char* ws = (char*)d_ws;
    size_t ofs = 0;
    u16* xb = (u16*)(ws + ofs);      ofs = align256(ofs + (size_t)N * D * sizeof(u16));
    int* counts = (int*)(ws + ofs);  ofs = align256(ofs + ((size_t)3 * N + 8) * sizeof(int));
    int* counters = counts + 3 * N;  // 3 ints, zeroed with counts
    int* cursor = (int*)(ws + ofs);  ofs = align256(ofs + (size_t)3 * N * sizeof(int));
    int* csr = (int*)(ws + ofs);     ofs = align256(ofs + (size_t)6 * E * sizeof(int));
    u16* Wp = (u16*)(ws + ofs);      ofs = align256(ofs + (size_t)28 * 8 * 64 * 8 * sizeof(u16));
    u16* AGF = (u16*)(ws + ofs);

    // chunk size from remaining ws: AGF = Nc * 768 bf16 = Nc*1536 B
    size_t avail = (ws_size > ofs) ? (ws_size - ofs) : 0;
    long long ncMax = (long long)(avail / 1536);
    int Nc = (int)((ncMax / 128) * 128);
    if (Nc > N) Nc = ((N + 127) / 128) * 128;
    if (Nc < 128) Nc = 128;
    const int NBs = Nc / 16;

    // prep
    zero_int_kernel<<<512, 256, 0, stream>>>(counts, 3 * N + 8);
    convert_kernel<<<1024, 256, 0, stream>>>((const float4*)x, (ushort4*)xb, N * D / 4);

    int cb = (E + 255) / 256;
    count_kernel<<<dim3(cb, 3), 256, 0, stream>>>(dst0, dst1, dst2, counts, N, E);

    int bpt = (N + 255) / 256;
    cursor_kernel<<<3 * bpt, 256, 0, stream>>>(counts, cursor, counters, N, bpt);

    scatter_kernel<1><<<cb, 256, 0, stream>>>(dst0, src0, cursor, csr, E);
    scatter_kernel<2><<<cb, 256, 0, stream>>>(dst1, src1, cursor + N, csr + (size_t)E, E);
    scatter_kernel<3><<<cb, 256, 0, stream>>>(dst2, src2, cursor + 2 * N, csr + (size_t)3 * E, E);

    pack_kernel<<<(28 * 8 * 64 + 255) / 256, 256, 0, stream>>>(WC, WA0, WA1, WA2, Wp);

    for (int n0 = 0; n0 < N; n0 += Nc) {
        int M = (N - n0 < Nc) ? (N - n0) : Nc;
        int ab = (6 * M + 3) / 4;
        agg_kernel<<<ab, 256, 0, stream>>>(xb, counts, cursor, csr, AGF, n0, M, N, E, NBs);
        final_gemm_kernel<<<(M + 127) / 128, 256, 0, stream>>>(x, AGF, Wp, bC,
                                                               (float*)d_out, n0, M, NBs);
    }
}